// Round 12
// baseline (4788.726 us; speedup 1.0000x reference)
//
#include <hip/hip_runtime.h>
#include <math.h>

#define NPTS    16384
#define DIM     128
#define KSEL    16
#define TSEL    18      // per-scanner sorted top list (16 + self + 1 margin)
#define NSCAN   8       // scanners per row (one per half-wave)
#define RPB     32      // rows per block
#define THREADS 256
#define CPSCAN  (NPTS / NSCAN)   // candidates per scanner = 2048 (contiguous)
#define NCAND   (NSCAN * TSEL)   // 144 candidates per row
#define CSTRIDE 145              // padded per-row stride (u64 keys)
#define KEYS_BYTES (RPB * CSTRIDE * 8)   // 37120

// BIT-EXACT numpy f32 pairwise-sum of x*x (AVX512 path) — validated R9.
__device__ __forceinline__ float np_sq_avx512(const float* __restrict__ x) {
    float s[16];
    #pragma unroll
    for (int L = 0; L < 16; ++L) {
        const float m0 = __fmul_rn(x[  0 + L], x[  0 + L]);
        const float m1 = __fmul_rn(x[ 16 + L], x[ 16 + L]);
        const float m2 = __fmul_rn(x[ 32 + L], x[ 32 + L]);
        const float m3 = __fmul_rn(x[ 48 + L], x[ 48 + L]);
        const float m4 = __fmul_rn(x[ 64 + L], x[ 64 + L]);
        const float m5 = __fmul_rn(x[ 80 + L], x[ 80 + L]);
        const float m6 = __fmul_rn(x[ 96 + L], x[ 96 + L]);
        const float m7 = __fmul_rn(x[112 + L], x[112 + L]);
        s[L] = __fadd_rn(
            __fadd_rn(__fadd_rn(m0, m1), __fadd_rn(m2, m3)),
            __fadd_rn(__fadd_rn(m4, m5), __fadd_rn(m6, m7)));
    }
    float u[8];
    #pragma unroll
    for (int i = 0; i < 8; ++i) u[i] = __fadd_rn(s[i], s[i + 8]);
    float v[4];
    #pragma unroll
    for (int i = 0; i < 4; ++i) v[i] = __fadd_rn(u[i], u[i + 4]);
    return __fadd_rn(__fadd_rn(v[0], v[2]), __fadd_rn(v[1], v[3]));
}

// scan-phase sq (capture key only; any consistent f32 approximation)
__device__ __forceinline__ float scan_sq(const float* __restrict__ xp) {
    const float4* x4 = (const float4*)xp;
    float a0 = 0.f, a1 = 0.f, a2 = 0.f, a3 = 0.f;
    #pragma unroll
    for (int g = 0; g < 32; ++g) {
        const float4 b = x4[g];
        a0 += b.x * b.x; a1 += b.y * b.y;
        a2 += b.z * b.z; a3 += b.w * b.w;
    }
    return (a0 + a1) + (a2 + a3);
}

__global__ __launch_bounds__(THREADS)
void sq_kernel(const float* __restrict__ X, float* __restrict__ sqws) {
    const int j = blockIdx.x * THREADS + threadIdx.x;
    sqws[j] = scan_sq(X + (size_t)j * DIM);
}

// launch_bounds(256,2): R9/R11-proven spill-free. (,3) spilled xi4 (VGPR 84,
// 38.5 GB HBM traffic, 2.8x regression). Do not raise.
template <bool USE_WS>
__global__ __launch_bounds__(THREADS, 2)
void knn_kernel(const float* __restrict__ X, const float* __restrict__ sqws,
                int* __restrict__ out) {
    // USE_WS:  LDS = 37.1 KB keys only.
    // !USE_WS: LDS = 64 KB sq table during scan, keys overlay after.
    constexpr int SMEM = USE_WS ? KEYS_BYTES : (NPTS * 4);
    __shared__ __align__(16) char smem[SMEM];
    unsigned long long* keys = (unsigned long long*)smem;
    float* sq_tab = (float*)smem;

    const int tid = threadIdx.x;
    const int s   = tid >> 5;       // scanner 0..7
    const int r   = tid & 31;       // row-in-block 0..31
    const int row = blockIdx.x * RPB + r;

    // own row in registers (128 VGPRs)
    float4 xi4[32];
    {
        const float4* xr = (const float4*)(X + (size_t)row * DIM);
        #pragma unroll
        for (int g = 0; g < 32; ++g) xi4[g] = xr[g];
    }

    // np-replica sq of OWN row (exact numpy-AVX512 pairwise) — rescore use
    const float sqi32 = np_sq_avx512(X + (size_t)row * DIM);

    if constexpr (!USE_WS) {
        // per-block sq table (one-time; ~8 MB L2-hot reads)
        #pragma unroll 1
        for (int q = 0; q < NPTS / THREADS; ++q) {
            const int j = tid + THREADS * q;
            sq_tab[j] = scan_sq(X + (size_t)j * DIM);
        }
        __syncthreads();
    }

    // sorted ascending top-TSEL (fp32 scan key, candidate index)
    float bv[TSEL]; int bi[TSEL];
    #pragma unroll
    for (int k = 0; k < TSEL; ++k) { bv[k] = 3.0e38f; bi[k] = 0; }

    // ---- scan: scanner s owns contiguous j in [s*2048, (s+1)*2048) ----
    // Candidates stream straight from global (L1/L2-resident broadcast);
    // no LDS traffic, no barriers in this loop.
    const int jbase = s * CPSCAN;
    #pragma unroll 1
    for (int jj = 0; jj < CPSCAN; ++jj) {
        const int jg = jbase + jj;
        const float4* bp = (const float4*)(X + (size_t)jg * DIM);
        // 4 independent accumulators: dep chain 32 FMA deep
        float d0 = 0.f, d1 = 0.f, d2 = 0.f, d3 = 0.f;
        #pragma unroll
        for (int g = 0; g < 32; g += 4) {
            const float4 b0 = bp[g],     b1 = bp[g + 1];
            const float4 b2 = bp[g + 2], b3 = bp[g + 3];
            d0 += b0.x * xi4[g].x;     d0 += b0.y * xi4[g].y;
            d0 += b0.z * xi4[g].z;     d0 += b0.w * xi4[g].w;
            d1 += b1.x * xi4[g+1].x;   d1 += b1.y * xi4[g+1].y;
            d1 += b1.z * xi4[g+1].z;   d1 += b1.w * xi4[g+1].w;
            d2 += b2.x * xi4[g+2].x;   d2 += b2.y * xi4[g+2].y;
            d2 += b2.z * xi4[g+2].z;   d2 += b2.w * xi4[g+2].w;
            d3 += b3.x * xi4[g+3].x;   d3 += b3.y * xi4[g+3].y;
            d3 += b3.z * xi4[g+3].z;   d3 += b3.w * xi4[g+3].w;
        }
        const float dot = (d0 + d1) + (d2 + d3);
        const float sqj = USE_WS ? sqws[jg] : sq_tab[jg];
        const float val = sqj - 2.f * dot;           // capture key (noise ok)

        if (val < bv[TSEL - 1]) {                    // rare after warm-up
            #pragma unroll
            for (int k = TSEL - 1; k >= 1; --k) {
                const bool m1 = val < bv[k - 1];
                const bool m2 = val < bv[k];
                bv[k] = m1 ? bv[k - 1] : (m2 ? val : bv[k]);
                bi[k] = m1 ? bi[k - 1] : (m2 ? jg  : bi[k]);
            }
            if (val < bv[0]) { bv[0] = val; bi[0] = jg; }
        }
    }

    if constexpr (!USE_WS) __syncthreads();  // done reading sq_tab (overlay)

    // ---- rescore: bit-replica of the np f32 pipeline (validated R9) ----
    #pragma unroll
    for (int k = 0; k < TSEL; ++k) {
        const int j = bi[k];                          // register (static idx)
        unsigned long long key;
        if (j == row) {
            key = 0xFFFFFFFFFFFFFFFFULL;              // self: excluded
        } else {
            const float* xjp = X + (size_t)j * DIM;
            const float4* xj = (const float4*)xjp;
            const float sqj32 = np_sq_avx512(xjp);
            float cacc = 0.f;
            #pragma unroll
            for (int g = 0; g < 32; ++g) {
                const float4 a = xi4[g], b = xj[g];
                cacc = __fmaf_rn(a.x, b.x, cacc);
                cacc = __fmaf_rn(a.y, b.y, cacc);
                cacc = __fmaf_rn(a.z, b.z, cacc);
                cacc = __fmaf_rn(a.w, b.w, cacc);
            }
            float d2c = __fsub_rn(__fadd_rn(sqi32, sqj32),
                                  __fmul_rn(2.0f, cacc));
            if (d2c < 0.0f) d2c = 0.0f;
            const float dist32 = sqrtf(d2c);          // f32 sqrt, correct rnd
            key = ((unsigned long long)__float_as_uint(dist32) << 32)
                  | (unsigned int)j;
        }
        keys[r * CSTRIDE + s * TSEL + k] = key;
    }
    __syncthreads();

    // ---- per-row top-16 by packed key ----
    if (tid < 32) {
        const int base = tid * CSTRIDE;
        const int i = blockIdx.x * RPB + tid;
        for (int m = 0; m < KSEL; ++m) {
            unsigned long long best = 0xFFFFFFFFFFFFFFFFULL; int bc = 0;
            for (int c2 = 0; c2 < NCAND; ++c2) {
                const unsigned long long v = keys[base + c2];
                if (v < best) { best = v; bc = c2; }
            }
            out[(size_t)i * KSEL + m] = (int)(best & 0xFFFFFFFFULL);
            keys[base + bc] = 0xFFFFFFFFFFFFFFFFULL;  // remove picked
        }
    }
}

extern "C" void kernel_launch(void* const* d_in, const int* in_sizes, int n_in,
                              void* d_out, int out_size, void* d_ws, size_t ws_size,
                              hipStream_t stream) {
    (void)in_sizes; (void)n_in; (void)out_size;
    const float* X = (const float*)d_in[0];
    int* out = (int*)d_out;
    if (ws_size >= (size_t)NPTS * sizeof(float)) {
        float* sqws = (float*)d_ws;
        sq_kernel<<<dim3(NPTS / THREADS), dim3(THREADS), 0, stream>>>(X, sqws);
        knn_kernel<true><<<dim3(NPTS / RPB), dim3(THREADS), 0, stream>>>(X, sqws, out);
    } else {
        knn_kernel<false><<<dim3(NPTS / RPB), dim3(THREADS), 0, stream>>>(X, nullptr, out);
    }
}

// Round 13
// 1475.245 us; speedup vs baseline: 3.2461x; 3.2461x over previous
//
#include <hip/hip_runtime.h>
#include <hip/hip_bf16.h>
#include <math.h>

#define NPTS    16384
#define DIM     128
#define KSEL    16
#define TSEL    18      // per-scanner sorted top list (16 + self + 1 margin)
#define NSCAN   8       // scanners per row = 2 col-half waves x 4 lane-groups
#define RPB     32      // rows per block (2 row-groups x 16)
#define THREADS 256
#define NTILES  512     // column tiles of 16 per wave (half of 16384 / 16)
#define NCAND   (NSCAN * TSEL)   // 144 candidates per row
#define CSTRIDE 145              // padded per-row stride (u64 keys)

typedef float f32x4  __attribute__((ext_vector_type(4)));
typedef short bf16x8 __attribute__((ext_vector_type(8)));

__device__ __forceinline__ unsigned short f2b(float f) {
    __hip_bfloat16 h = __float2bfloat16(f);   // RTNE
    return *(unsigned short*)&h;
}

// BIT-EXACT numpy f32 pairwise-sum of x*x (AVX512 path) — validated R9.
__device__ __forceinline__ float np_sq_avx512(const float* __restrict__ x) {
    float s[16];
    #pragma unroll
    for (int L = 0; L < 16; ++L) {
        const float m0 = __fmul_rn(x[  0 + L], x[  0 + L]);
        const float m1 = __fmul_rn(x[ 16 + L], x[ 16 + L]);
        const float m2 = __fmul_rn(x[ 32 + L], x[ 32 + L]);
        const float m3 = __fmul_rn(x[ 48 + L], x[ 48 + L]);
        const float m4 = __fmul_rn(x[ 64 + L], x[ 64 + L]);
        const float m5 = __fmul_rn(x[ 80 + L], x[ 80 + L]);
        const float m6 = __fmul_rn(x[ 96 + L], x[ 96 + L]);
        const float m7 = __fmul_rn(x[112 + L], x[112 + L]);
        s[L] = __fadd_rn(
            __fadd_rn(__fadd_rn(m0, m1), __fadd_rn(m2, m3)),
            __fadd_rn(__fadd_rn(m4, m5), __fadd_rn(m6, m7)));
    }
    float u[8];
    #pragma unroll
    for (int i = 0; i < 8; ++i) u[i] = __fadd_rn(s[i], s[i + 8]);
    float v[4];
    #pragma unroll
    for (int i = 0; i < 4; ++i) v[i] = __fadd_rn(u[i], u[i + 4]);
    return __fadd_rn(__fadd_rn(v[0], v[2]), __fadd_rn(v[1], v[3]));
}

// scan-phase sq (capture key only)
__device__ __forceinline__ float scan_sq(const float* __restrict__ xp) {
    const float4* x4 = (const float4*)xp;
    float a0 = 0.f, a1 = 0.f, a2 = 0.f, a3 = 0.f;
    #pragma unroll
    for (int g = 0; g < 32; ++g) {
        const float4 b = x4[g];
        a0 += b.x * b.x; a1 += b.y * b.y;
        a2 += b.z * b.z; a3 += b.w * b.w;
    }
    return (a0 + a1) + (a2 + a3);
}

__global__ __launch_bounds__(THREADS)
void sq_kernel(const float* __restrict__ X, float* __restrict__ sqws) {
    const int j = blockIdx.x * THREADS + threadIdx.x;
    sqws[j] = 0.5f * scan_sq(X + (size_t)j * DIM);   // half-scale scan key
}

__global__ __launch_bounds__(THREADS)
void cvt_kernel(const float* __restrict__ X, unsigned short* __restrict__ Xb) {
    const size_t i = ((size_t)blockIdx.x * THREADS + threadIdx.x) * 8;
    const float4 v0 = *(const float4*)(X + i);
    const float4 v1 = *(const float4*)(X + i + 4);
    ushort4 o0, o1;
    o0.x = f2b(v0.x); o0.y = f2b(v0.y); o0.z = f2b(v0.z); o0.w = f2b(v0.w);
    o1.x = f2b(v1.x); o1.y = f2b(v1.y); o1.z = f2b(v1.z); o1.w = f2b(v1.w);
    *(ushort4*)(Xb + i) = o0;
    *(ushort4*)(Xb + i + 4) = o1;
}

// launch_bounds(256,2): R9/R11-proven spill-free. (,3) spilled -> 2.8x
// regression (R10). Do not raise.
template <bool HAS_WS>
__global__ __launch_bounds__(THREADS, 2)
void knn_kernel(const float* __restrict__ X, const float* __restrict__ sqws,
                const unsigned short* __restrict__ Xb, int* __restrict__ out) {
    // LDS: 64 KB sq table (half-scale fp32) during scan; u64 keys overlay
    // after (37.1 KB). 2 blocks/CU.
    __shared__ __align__(16) char smem[NPTS * 4];
    float* sqh = (float*)smem;
    unsigned long long* keys = (unsigned long long*)smem;

    const int tid  = threadIdx.x;
    const int w    = tid >> 6;        // wave 0..3
    const int l    = tid & 63;        // lane
    const int lg   = l >> 4;          // lane-group 0..3
    const int l15  = l & 15;
    const int rloc = (w >> 1) * 16 + l15;           // local row 0..31
    const int grow = blockIdx.x * RPB + rloc;       // global query row
    const int colbase = (w & 1) * (NPTS / 2);       // column half
    const int s = (w & 1) * 4 + lg;                 // scanner 0..7

    // ---- sq table into LDS ----
    if constexpr (HAS_WS) {
        #pragma unroll
        for (int q = 0; q < NPTS / THREADS / 4; ++q)   // 16 x float4
            ((float4*)sqh)[tid + THREADS * q] =
                ((const float4*)sqws)[tid + THREADS * q];
    } else {
        #pragma unroll 1
        for (int q = 0; q < NPTS / THREADS; ++q) {
            const int j = tid + THREADS * q;
            sqh[j] = 0.5f * scan_sq(X + (size_t)j * DIM);
        }
    }
    __syncthreads();

    // ---- B fragments: NEGATED query row, k-slices m*32 + lg*8 .. +8 ----
    // A and B use the SAME lane->k mapping, so any k-permutation error
    // cancels (dot is k-invariant). Only C/D layout (HW-verified) matters.
    bf16x8 nb[4];
    if constexpr (HAS_WS) {
        const unsigned short* xr = Xb + (size_t)grow * DIM + lg * 8;
        #pragma unroll
        for (int m = 0; m < 4; ++m) {
            union { bf16x8 h; uint4 u; } t;
            t.h = *(const bf16x8*)(xr + m * 32);
            t.u.x ^= 0x80008000u; t.u.y ^= 0x80008000u;
            t.u.z ^= 0x80008000u; t.u.w ^= 0x80008000u;
            nb[m] = t.h;
        }
    } else {
        const float* xr = X + (size_t)grow * DIM + lg * 8;
        #pragma unroll
        for (int m = 0; m < 4; ++m) {
            bf16x8 h;
            #pragma unroll
            for (int e = 0; e < 8; ++e) h[e] = (short)f2b(-xr[m * 32 + e]);
            nb[m] = h;
        }
    }

    // sorted ascending top-TSEL (scan key = 0.5*sq_j - dot, fp32 acc)
    float bv[TSEL]; int bi[TSEL];
    #pragma unroll
    for (int k = 0; k < TSEL; ++k) { bv[k] = 3.0e38f; bi[k] = 0; }

    // ---- MFMA scan over this wave's 512 column tiles of 16 ----
    const unsigned short* ap =
        HAS_WS ? Xb + (size_t)(colbase + l15) * DIM + lg * 8 : nullptr;
    const float* apf =
        HAS_WS ? nullptr : X + (size_t)(colbase + l15) * DIM + lg * 8;

    #pragma unroll 1
    for (int t = 0; t < NTILES; ++t) {
        const int cb = colbase + t * 16;
        bf16x8 a0, a1, a2, a3;
        if constexpr (HAS_WS) {
            a0 = *(const bf16x8*)(ap);
            a1 = *(const bf16x8*)(ap + 32);
            a2 = *(const bf16x8*)(ap + 64);
            a3 = *(const bf16x8*)(ap + 96);
            ap += 16 * DIM;
        } else {
            #pragma unroll
            for (int e = 0; e < 8; ++e) {
                a0[e] = (short)f2b(apf[e]);
                a1[e] = (short)f2b(apf[32 + e]);
                a2[e] = (short)f2b(apf[64 + e]);
                a3[e] = (short)f2b(apf[96 + e]);
            }
            apf += 16 * DIM;
        }
        // C-init = 0.5*sq of this lane-group's 4 candidates (broadcast read)
        f32x4 acc = *(const f32x4*)&sqh[cb + lg * 4];
        acc = __builtin_amdgcn_mfma_f32_16x16x32_bf16(a0, nb[0], acc, 0, 0, 0);
        acc = __builtin_amdgcn_mfma_f32_16x16x32_bf16(a1, nb[1], acc, 0, 0, 0);
        acc = __builtin_amdgcn_mfma_f32_16x16x32_bf16(a2, nb[2], acc, 0, 0, 0);
        acc = __builtin_amdgcn_mfma_f32_16x16x32_bf16(a3, nb[3], acc, 0, 0, 0);
        // acc[r] = 0.5*sq_cand - dot(x_cand, x_row), cand = cb + lg*4 + r
        #pragma unroll
        for (int r = 0; r < 4; ++r) {
            const float val = acc[r];
            if (val < bv[TSEL - 1]) {                 // rare after warm-up
                const int jg = cb + lg * 4 + r;
                #pragma unroll
                for (int k = TSEL - 1; k >= 1; --k) {
                    const bool m1 = val < bv[k - 1];
                    const bool m2 = val < bv[k];
                    bv[k] = m1 ? bv[k - 1] : (m2 ? val : bv[k]);
                    bi[k] = m1 ? bi[k - 1] : (m2 ? jg  : bi[k]);
                }
                if (val < bv[0]) { bv[0] = val; bi[0] = jg; }
            }
        }
    }
    __syncthreads();   // done reading sqh; keys overlay begins

    // ---- rescore: bit-replica of the np f32 pipeline (validated R9) ----
    // own row in fp32 registers (loaded after scan to keep scan VGPR low)
    float4 xi4[32];
    {
        const float4* xr = (const float4*)(X + (size_t)grow * DIM);
        #pragma unroll
        for (int g = 0; g < 32; ++g) xi4[g] = xr[g];
    }
    const float sqi32 = np_sq_avx512(X + (size_t)grow * DIM);

    #pragma unroll
    for (int k = 0; k < TSEL; ++k) {
        const int j = bi[k];                          // register (static idx)
        unsigned long long key;
        if (j == grow) {
            key = 0xFFFFFFFFFFFFFFFFULL;              // self: excluded
        } else {
            const float* xjp = X + (size_t)j * DIM;
            const float4* xj = (const float4*)xjp;
            const float sqj32 = np_sq_avx512(xjp);
            float cacc = 0.f;
            #pragma unroll
            for (int g = 0; g < 32; ++g) {
                const float4 a = xi4[g], b = xj[g];
                cacc = __fmaf_rn(a.x, b.x, cacc);
                cacc = __fmaf_rn(a.y, b.y, cacc);
                cacc = __fmaf_rn(a.z, b.z, cacc);
                cacc = __fmaf_rn(a.w, b.w, cacc);
            }
            float d2c = __fsub_rn(__fadd_rn(sqi32, sqj32),
                                  __fmul_rn(2.0f, cacc));
            if (d2c < 0.0f) d2c = 0.0f;
            const float dist32 = sqrtf(d2c);          // f32 sqrt, correct rnd
            key = ((unsigned long long)__float_as_uint(dist32) << 32)
                  | (unsigned int)j;
        }
        keys[rloc * CSTRIDE + s * TSEL + k] = key;
    }
    __syncthreads();

    // ---- per-row top-16 by packed key ----
    if (tid < RPB) {
        const int base = tid * CSTRIDE;
        const int i = blockIdx.x * RPB + tid;
        for (int m = 0; m < KSEL; ++m) {
            unsigned long long best = 0xFFFFFFFFFFFFFFFFULL; int bc = 0;
            for (int c2 = 0; c2 < NCAND; ++c2) {
                const unsigned long long v = keys[base + c2];
                if (v < best) { best = v; bc = c2; }
            }
            out[(size_t)i * KSEL + m] = (int)(best & 0xFFFFFFFFULL);
            keys[base + bc] = 0xFFFFFFFFFFFFFFFFULL;  // remove picked
        }
    }
}

extern "C" void kernel_launch(void* const* d_in, const int* in_sizes, int n_in,
                              void* d_out, int out_size, void* d_ws, size_t ws_size,
                              hipStream_t stream) {
    (void)in_sizes; (void)n_in; (void)out_size;
    const float* X = (const float*)d_in[0];
    int* out = (int*)d_out;
    const size_t WS_NEED = (size_t)NPTS * 4 + (size_t)NPTS * DIM * 2;
    if (ws_size >= WS_NEED) {
        float* sqws = (float*)d_ws;
        unsigned short* Xb = (unsigned short*)((char*)d_ws + (size_t)NPTS * 4);
        sq_kernel<<<dim3(NPTS / THREADS), dim3(THREADS), 0, stream>>>(X, sqws);
        cvt_kernel<<<dim3(NPTS * DIM / 8 / THREADS), dim3(THREADS), 0, stream>>>(X, Xb);
        knn_kernel<true><<<dim3(NPTS / RPB), dim3(THREADS), 0, stream>>>(X, sqws, Xb, out);
    } else {
        knn_kernel<false><<<dim3(NPTS / RPB), dim3(THREADS), 0, stream>>>(X, nullptr, nullptr, out);
    }
}

// Round 14
// 1458.323 us; speedup vs baseline: 3.2837x; 1.0116x over previous
//
#include <hip/hip_runtime.h>
#include <hip/hip_bf16.h>
#include <math.h>

#define NPTS    16384
#define DIM     128
#define KSEL    16
#define TSEL    18      // per-scanner sorted top list (16 + self + 1 margin)
#define NSCAN   8       // scanners per row = 2 col-half waves x 4 lane-groups
#define RPB     32      // rows per block (2 row-groups x 16)
#define THREADS 256
#define NTILES  512     // column tiles of 16 per wave (half of 16384 / 16)
#define NCAND   (NSCAN * TSEL)   // 144 candidates per row
#define CSTRIDE 145              // padded per-row stride (u64 keys)
#define KEYS_BYTES (RPB * CSTRIDE * 8)   // 37120 -> 4 blocks/CU

typedef float f32x4  __attribute__((ext_vector_type(4)));
typedef short bf16x8 __attribute__((ext_vector_type(8)));

__device__ __forceinline__ unsigned short f2b(float f) {
    __hip_bfloat16 h = __float2bfloat16(f);   // RTNE
    return *(unsigned short*)&h;
}

// BIT-EXACT numpy f32 pairwise-sum of x*x (AVX512 path) — validated R9.
__device__ __forceinline__ float np_sq_avx512(const float* __restrict__ x) {
    float s[16];
    #pragma unroll
    for (int L = 0; L < 16; ++L) {
        const float m0 = __fmul_rn(x[  0 + L], x[  0 + L]);
        const float m1 = __fmul_rn(x[ 16 + L], x[ 16 + L]);
        const float m2 = __fmul_rn(x[ 32 + L], x[ 32 + L]);
        const float m3 = __fmul_rn(x[ 48 + L], x[ 48 + L]);
        const float m4 = __fmul_rn(x[ 64 + L], x[ 64 + L]);
        const float m5 = __fmul_rn(x[ 80 + L], x[ 80 + L]);
        const float m6 = __fmul_rn(x[ 96 + L], x[ 96 + L]);
        const float m7 = __fmul_rn(x[112 + L], x[112 + L]);
        s[L] = __fadd_rn(
            __fadd_rn(__fadd_rn(m0, m1), __fadd_rn(m2, m3)),
            __fadd_rn(__fadd_rn(m4, m5), __fadd_rn(m6, m7)));
    }
    float u[8];
    #pragma unroll
    for (int i = 0; i < 8; ++i) u[i] = __fadd_rn(s[i], s[i + 8]);
    float v[4];
    #pragma unroll
    for (int i = 0; i < 4; ++i) v[i] = __fadd_rn(u[i], u[i + 4]);
    return __fadd_rn(__fadd_rn(v[0], v[2]), __fadd_rn(v[1], v[3]));
}

// scan-phase sq (capture key only)
__device__ __forceinline__ float scan_sq(const float* __restrict__ xp) {
    const float4* x4 = (const float4*)xp;
    float a0 = 0.f, a1 = 0.f, a2 = 0.f, a3 = 0.f;
    #pragma unroll
    for (int g = 0; g < 32; ++g) {
        const float4 b = x4[g];
        a0 += b.x * b.x; a1 += b.y * b.y;
        a2 += b.z * b.z; a3 += b.w * b.w;
    }
    return (a0 + a1) + (a2 + a3);
}

__global__ __launch_bounds__(THREADS)
void sq_kernel(const float* __restrict__ X, float* __restrict__ sqws) {
    const int j = blockIdx.x * THREADS + threadIdx.x;
    sqws[j] = 0.5f * scan_sq(X + (size_t)j * DIM);   // half-scale scan key
}

__global__ __launch_bounds__(THREADS)
void cvt_kernel(const float* __restrict__ X, unsigned short* __restrict__ Xb) {
    const size_t i = ((size_t)blockIdx.x * THREADS + threadIdx.x) * 8;
    const float4 v0 = *(const float4*)(X + i);
    const float4 v1 = *(const float4*)(X + i + 4);
    ushort4 o0, o1;
    o0.x = f2b(v0.x); o0.y = f2b(v0.y); o0.z = f2b(v0.z); o0.w = f2b(v0.w);
    o1.x = f2b(v1.x); o1.y = f2b(v1.y); o1.z = f2b(v1.z); o1.w = f2b(v1.w);
    *(ushort4*)(Xb + i) = o0;
    *(ushort4*)(Xb + i + 4) = o1;
}

// launch_bounds(256,2): R9/R11/R13-proven spill-free. (,3) spilled -> 2.8x
// regression (R10). Do not raise.
template <bool HAS_WS>
__global__ __launch_bounds__(THREADS, 2)
void knn_kernel(const float* __restrict__ X, const float* __restrict__ sqws,
                const unsigned short* __restrict__ Xb, int* __restrict__ out) {
    // HAS_WS:  LDS = 37.1 KB keys only -> 4 blocks/CU (VGPR-bound 16 wv/CU).
    // !HAS_WS: LDS = 64 KB sq table during scan, keys overlay after.
    constexpr int SMEM = HAS_WS ? KEYS_BYTES : (NPTS * 4);
    __shared__ __align__(16) char smem[SMEM];
    float* sqh = (float*)smem;
    unsigned long long* keys = (unsigned long long*)smem;

    const int tid  = threadIdx.x;
    const int w    = tid >> 6;        // wave 0..3
    const int l    = tid & 63;        // lane
    const int lg   = l >> 4;          // lane-group 0..3
    const int l15  = l & 15;
    const int rloc = (w >> 1) * 16 + l15;           // local row 0..31
    const int grow = blockIdx.x * RPB + rloc;       // global query row
    const int colbase = (w & 1) * (NPTS / 2);       // column half
    const int s = (w & 1) * 4 + lg;                 // scanner 0..7

    if constexpr (!HAS_WS) {
        // per-block sq table (one-time; L2-hot reads)
        #pragma unroll 1
        for (int q = 0; q < NPTS / THREADS; ++q) {
            const int j = tid + THREADS * q;
            sqh[j] = 0.5f * scan_sq(X + (size_t)j * DIM);
        }
        __syncthreads();
    }

    // ---- B fragments: NEGATED query row, k-slices m*32 + lg*8 .. +8 ----
    // A and B use the SAME lane->k mapping, so any k-permutation error
    // cancels (dot is k-invariant). Only C/D layout (HW-verified) matters.
    bf16x8 nb[4];
    if constexpr (HAS_WS) {
        const unsigned short* xr = Xb + (size_t)grow * DIM + lg * 8;
        #pragma unroll
        for (int m = 0; m < 4; ++m) {
            union { bf16x8 h; uint4 u; } t;
            t.h = *(const bf16x8*)(xr + m * 32);
            t.u.x ^= 0x80008000u; t.u.y ^= 0x80008000u;
            t.u.z ^= 0x80008000u; t.u.w ^= 0x80008000u;
            nb[m] = t.h;
        }
    } else {
        const float* xr = X + (size_t)grow * DIM + lg * 8;
        #pragma unroll
        for (int m = 0; m < 4; ++m) {
            bf16x8 h;
            #pragma unroll
            for (int e = 0; e < 8; ++e) h[e] = (short)f2b(-xr[m * 32 + e]);
            nb[m] = h;
        }
    }

    // sorted ascending top-TSEL (scan key = 0.5*sq_j - dot, fp32 acc)
    float bv[TSEL]; int bi[TSEL];
    #pragma unroll
    for (int k = 0; k < TSEL; ++k) { bv[k] = 3.0e38f; bi[k] = 0; }

    // ---- MFMA scan over this wave's 512 column tiles of 16 ----
    const unsigned short* ap =
        HAS_WS ? Xb + (size_t)(colbase + l15) * DIM + lg * 8 : nullptr;
    const float* apf =
        HAS_WS ? nullptr : X + (size_t)(colbase + l15) * DIM + lg * 8;

    #pragma unroll 1
    for (int t = 0; t < NTILES; ++t) {
        const int cb = colbase + t * 16;
        bf16x8 a0, a1, a2, a3;
        if constexpr (HAS_WS) {
            a0 = *(const bf16x8*)(ap);
            a1 = *(const bf16x8*)(ap + 32);
            a2 = *(const bf16x8*)(ap + 64);
            a3 = *(const bf16x8*)(ap + 96);
            ap += 16 * DIM;
        } else {
            #pragma unroll
            for (int e = 0; e < 8; ++e) {
                a0[e] = (short)f2b(apf[e]);
                a1[e] = (short)f2b(apf[32 + e]);
                a2[e] = (short)f2b(apf[64 + e]);
                a3[e] = (short)f2b(apf[96 + e]);
            }
            apf += 16 * DIM;
        }
        // C-init = 0.5*sq of this lane-group's 4 candidates.
        // HAS_WS: straight from global (64 KB table, L1/L2-hot broadcast) —
        // this is what freed 27 KB of LDS and doubled occupancy.
        f32x4 acc;
        if constexpr (HAS_WS) acc = *(const f32x4*)&sqws[cb + lg * 4];
        else                  acc = *(const f32x4*)&sqh [cb + lg * 4];
        acc = __builtin_amdgcn_mfma_f32_16x16x32_bf16(a0, nb[0], acc, 0, 0, 0);
        acc = __builtin_amdgcn_mfma_f32_16x16x32_bf16(a1, nb[1], acc, 0, 0, 0);
        acc = __builtin_amdgcn_mfma_f32_16x16x32_bf16(a2, nb[2], acc, 0, 0, 0);
        acc = __builtin_amdgcn_mfma_f32_16x16x32_bf16(a3, nb[3], acc, 0, 0, 0);
        // acc[r] = 0.5*sq_cand - dot(x_cand, x_row), cand = cb + lg*4 + r
        #pragma unroll
        for (int r = 0; r < 4; ++r) {
            const float val = acc[r];
            if (val < bv[TSEL - 1]) {                 // rare after warm-up
                const int jg = cb + lg * 4 + r;
                #pragma unroll
                for (int k = TSEL - 1; k >= 1; --k) {
                    const bool m1 = val < bv[k - 1];
                    const bool m2 = val < bv[k];
                    bv[k] = m1 ? bv[k - 1] : (m2 ? val : bv[k]);
                    bi[k] = m1 ? bi[k - 1] : (m2 ? jg  : bi[k]);
                }
                if (val < bv[0]) { bv[0] = val; bi[0] = jg; }
            }
        }
    }

    if constexpr (!HAS_WS) __syncthreads();  // done reading sqh (overlay)

    // ---- rescore: bit-replica of the np f32 pipeline (validated R9) ----
    // own row in fp32 registers (loaded after scan to keep scan VGPR low)
    float4 xi4[32];
    {
        const float4* xr = (const float4*)(X + (size_t)grow * DIM);
        #pragma unroll
        for (int g = 0; g < 32; ++g) xi4[g] = xr[g];
    }
    const float sqi32 = np_sq_avx512(X + (size_t)grow * DIM);

    #pragma unroll
    for (int k = 0; k < TSEL; ++k) {
        const int j = bi[k];                          // register (static idx)
        unsigned long long key;
        if (j == grow) {
            key = 0xFFFFFFFFFFFFFFFFULL;              // self: excluded
        } else {
            const float* xjp = X + (size_t)j * DIM;
            const float4* xj = (const float4*)xjp;
            const float sqj32 = np_sq_avx512(xjp);
            float cacc = 0.f;
            #pragma unroll
            for (int g = 0; g < 32; ++g) {
                const float4 a = xi4[g], b = xj[g];
                cacc = __fmaf_rn(a.x, b.x, cacc);
                cacc = __fmaf_rn(a.y, b.y, cacc);
                cacc = __fmaf_rn(a.z, b.z, cacc);
                cacc = __fmaf_rn(a.w, b.w, cacc);
            }
            float d2c = __fsub_rn(__fadd_rn(sqi32, sqj32),
                                  __fmul_rn(2.0f, cacc));
            if (d2c < 0.0f) d2c = 0.0f;
            const float dist32 = sqrtf(d2c);          // f32 sqrt, correct rnd
            key = ((unsigned long long)__float_as_uint(dist32) << 32)
                  | (unsigned int)j;
        }
        keys[rloc * CSTRIDE + s * TSEL + k] = key;
    }
    __syncthreads();

    // ---- per-row top-16 by packed key ----
    if (tid < RPB) {
        const int base = tid * CSTRIDE;
        const int i = blockIdx.x * RPB + tid;
        for (int m = 0; m < KSEL; ++m) {
            unsigned long long best = 0xFFFFFFFFFFFFFFFFULL; int bc = 0;
            for (int c2 = 0; c2 < NCAND; ++c2) {
                const unsigned long long v = keys[base + c2];
                if (v < best) { best = v; bc = c2; }
            }
            out[(size_t)i * KSEL + m] = (int)(best & 0xFFFFFFFFULL);
            keys[base + bc] = 0xFFFFFFFFFFFFFFFFULL;  // remove picked
        }
    }
}

extern "C" void kernel_launch(void* const* d_in, const int* in_sizes, int n_in,
                              void* d_out, int out_size, void* d_ws, size_t ws_size,
                              hipStream_t stream) {
    (void)in_sizes; (void)n_in; (void)out_size;
    const float* X = (const float*)d_in[0];
    int* out = (int*)d_out;
    const size_t WS_NEED = (size_t)NPTS * 4 + (size_t)NPTS * DIM * 2;
    if (ws_size >= WS_NEED) {
        float* sqws = (float*)d_ws;
        unsigned short* Xb = (unsigned short*)((char*)d_ws + (size_t)NPTS * 4);
        sq_kernel<<<dim3(NPTS / THREADS), dim3(THREADS), 0, stream>>>(X, sqws);
        cvt_kernel<<<dim3(NPTS * DIM / 8 / THREADS), dim3(THREADS), 0, stream>>>(X, Xb);
        knn_kernel<true><<<dim3(NPTS / RPB), dim3(THREADS), 0, stream>>>(X, sqws, Xb, out);
    } else {
        knn_kernel<false><<<dim3(NPTS / RPB), dim3(THREADS), 0, stream>>>(X, nullptr, nullptr, out);
    }
}